// Round 2
// baseline (119.124 us; speedup 1.0000x reference)
//
#include <hip/hip_runtime.h>
#include <stdint.h>

// Problem constants
#define N_      8
#define IC_     16
#define C1_     2048
#define H_      56
#define W_      56
#define WT_     14            // w-tile per block (56 = 4*14)
#define NWT_    4
#define THREADS_ 512
#define ROWU_   10            // LDS row stride in dwords (7 used + 3 pad -> 40B)

// One block = (n, h, w-tile of 14). Phase 1: all 2048 conv channels -> LDS (bf16 packed).
// Phase 2: gather 4 random channels per output j, max, write.
__global__ __launch_bounds__(THREADS_, 4)
void rptn_fused(const float* __restrict__ x,
                const float* __restrict__ W1,
                const float* __restrict__ b1,
                const int* __restrict__ idx,   // harness passes integer inputs as int32
                float* __restrict__ out)
{
    __shared__ uint32_t s1[C1_ * ROWU_];   // 80 KB -> 2 blocks/CU

    const int tid = threadIdx.x;
    const int b   = blockIdx.x;
    const int n   = b / (H_ * NWT_);
    const int rem = b % (H_ * NWT_);
    const int h   = rem / NWT_;
    const int w0  = (rem % NWT_) * WT_;

    // ---------------- Phase 1: depthwise-grouped conv into LDS ----------------
    #pragma unroll 1
    for (int pass = 0; pass < 4; ++pass) {
        const int c  = pass * THREADS_ + tid;          // this thread's out1 channel
        // 64 consecutive c per wave always share ci = c/128 -> wave-uniform
        const int ci = __builtin_amdgcn_readfirstlane(c >> 7);

        // 3x16 input window (zero-padded), wave-uniform -> scalar loads
        float xr[3][16];
        const float* xb = x + (size_t)((n * IC_ + ci) * H_) * W_;
        #pragma unroll
        for (int rr = 0; rr < 3; ++rr) {
            const int r = h - 1 + rr;
            const bool rok = ((unsigned)r < (unsigned)H_);
            #pragma unroll
            for (int cc = 0; cc < 16; ++cc) {
                const int col = w0 - 1 + cc;
                const bool ok = rok && ((unsigned)col < (unsigned)W_);
                xr[rr][cc] = ok ? xb[r * W_ + col] : 0.0f;
            }
        }

        // per-lane weights + bias (L2-resident)
        float w[9];
        const float* wp = W1 + c * 9;
        #pragma unroll
        for (int k = 0; k < 9; ++k) w[k] = wp[k];
        const float bias = b1[c];

        float acc[WT_];
        #pragma unroll
        for (int p = 0; p < WT_; ++p) acc[p] = bias;

        #pragma unroll
        for (int dr = 0; dr < 3; ++dr) {
            #pragma unroll
            for (int dc = 0; dc < 3; ++dc) {
                const float wk = w[dr * 3 + dc];
                #pragma unroll
                for (int p = 0; p < WT_; ++p)
                    acc[p] = fmaf(xr[dr][p + dc], wk, acc[p]);
            }
        }

        // pack 14 f32 -> 7 dwords of bf16 pairs (RNE), store LDS row c
        uint32_t pk[7];
        #pragma unroll
        for (int k = 0; k < 7; ++k) {
            uint32_t u0 = __float_as_uint(acc[2 * k]);
            uint32_t u1 = __float_as_uint(acc[2 * k + 1]);
            u0 = (u0 + 0x7fffu + ((u0 >> 16) & 1u)) >> 16;
            u1 = (u1 + 0x7fffu + ((u1 >> 16) & 1u)) >> 16;
            pk[k] = u0 | (u1 << 16);
        }
        uint32_t* row = &s1[c * ROWU_];
        *(uint2*)(row + 0) = make_uint2(pk[0], pk[1]);
        *(uint2*)(row + 2) = make_uint2(pk[2], pk[3]);
        *(uint2*)(row + 4) = make_uint2(pk[4], pk[5]);
        row[6] = pk[6];
    }

    __syncthreads();

    // ---------------- Phase 2: gather + max-over-4 + coalesced store ----------------
    #pragma unroll 1
    for (int pass = 0; pass < 4; ++pass) {
        const int j = pass * THREADS_ + tid;           // output channel
        const int4 iv = *(const int4*)(idx + 4 * j);   // 16B-aligned
        const int c0 = iv.x & (C1_ - 1);
        const int c1 = iv.y & (C1_ - 1);
        const int c2 = iv.z & (C1_ - 1);
        const int c3 = iv.w & (C1_ - 1);

        float m[WT_];
        {
            const uint32_t* row = &s1[c0 * ROWU_];
            const uint2 a = *(const uint2*)(row);
            const uint2 bq = *(const uint2*)(row + 2);
            const uint2 cq = *(const uint2*)(row + 4);
            const uint32_t d = row[6];
            const uint32_t u[7] = {a.x, a.y, bq.x, bq.y, cq.x, cq.y, d};
            #pragma unroll
            for (int k = 0; k < 7; ++k) {
                m[2 * k]     = __uint_as_float(u[k] << 16);
                m[2 * k + 1] = __uint_as_float(u[k] & 0xffff0000u);
            }
        }
        #pragma unroll
        for (int g = 1; g < 4; ++g) {
            const int cg = (g == 1) ? c1 : (g == 2) ? c2 : c3;
            const uint32_t* row = &s1[cg * ROWU_];
            const uint2 a = *(const uint2*)(row);
            const uint2 bq = *(const uint2*)(row + 2);
            const uint2 cq = *(const uint2*)(row + 4);
            const uint32_t d = row[6];
            const uint32_t u[7] = {a.x, a.y, bq.x, bq.y, cq.x, cq.y, d};
            #pragma unroll
            for (int k = 0; k < 7; ++k) {
                m[2 * k]     = fmaxf(m[2 * k],     __uint_as_float(u[k] << 16));
                m[2 * k + 1] = fmaxf(m[2 * k + 1], __uint_as_float(u[k] & 0xffff0000u));
            }
        }

        float* op = out + (size_t)(n * C1_ + j) * (H_ * W_) + h * W_ + w0;
        #pragma unroll
        for (int k = 0; k < 7; ++k)
            *(float2*)(op + 2 * k) = make_float2(m[2 * k], m[2 * k + 1]);
    }
}

extern "C" void kernel_launch(void* const* d_in, const int* in_sizes, int n_in,
                              void* d_out, int out_size, void* d_ws, size_t ws_size,
                              hipStream_t stream)
{
    const float* x   = (const float*)d_in[0];
    const float* W1  = (const float*)d_in[1];
    const float* b1  = (const float*)d_in[2];
    const int* idxp  = (const int*)d_in[3];
    float* out       = (float*)d_out;

    dim3 grid(N_ * H_ * NWT_);   // 8*56*4 = 1792 blocks
    dim3 block(THREADS_);
    hipLaunchKernelGGL(rptn_fused, grid, block, 0, stream, x, W1, b1, idxp, out);
}